// Round 1
// baseline (9538.778 us; speedup 1.0000x reference)
//
#include <hip/hip_runtime.h>
#include <math.h>

#define ROI 400
#define HEADS 4
#define DH 100
#define NB 64
#define HIDF 800
#define NC 2
#define KPOOL 280
#define ATT_SCALE 0.1f

// ---------------------------------------------------------------- preprocess
__global__ __launch_bounds__(256) void pre_reduce_kernel(const float* __restrict__ in,
                                                         float* __restrict__ meanb,
                                                         float* __restrict__ stdb) {
  int b = blockIdx.x;
  const float* p = in + (size_t)b * ROI * (2 * ROI);
  double s = 0.0, ss = 0.0;
  const int n = ROI * ROI;
  for (int e = threadIdx.x; e < n; e += blockDim.x) {
    int r = e / ROI, c = e % ROI;
    float v = log10f(p[(size_t)r * (2 * ROI) + ROI + c] + 1.0f);
    s += v; ss += (double)v * (double)v;
  }
  __shared__ double rs[256], rss[256];
  rs[threadIdx.x] = s; rss[threadIdx.x] = ss;
  __syncthreads();
  for (int st = 128; st > 0; st >>= 1) {
    if (threadIdx.x < st) { rs[threadIdx.x] += rs[threadIdx.x + st]; rss[threadIdx.x] += rss[threadIdx.x + st]; }
    __syncthreads();
  }
  if (threadIdx.x == 0) {
    double mean = rs[0] / n;
    double var = (rss[0] - rs[0] * rs[0] / n) / (double)(n - 1);
    meanb[b] = (float)mean;
    stdb[b]  = (float)(sqrt(var) + 1e-6);
  }
}

__global__ __launch_bounds__(256) void build_xm_kernel(const float* __restrict__ in,
                                                       const float* __restrict__ sel,
                                                       const float* __restrict__ meanb,
                                                       const float* __restrict__ stdb,
                                                       float* __restrict__ X, float* __restrict__ M) {
  size_t e = (size_t)blockIdx.x * blockDim.x + threadIdx.x;
  const size_t total = (size_t)NB * ROI * ROI;
  if (e >= total) return;
  int c = (int)(e % ROI);
  int r = (int)((e / ROI) % ROI);
  int b = (int)(e / ((size_t)ROI * ROI));
  const float* row = in + ((size_t)b * ROI + r) * (2 * ROI);
  X[e] = row[c];
  float v = log10f(row[ROI + c] + 1.0f);
  float sg = 1.0f / (1.0f + expf(-sel[r * ROI + c]));
  M[e] = ((v - meanb[b]) / stdb[b]) * sg;
}

// ---------------------------------------------------------------- GEMM
// C[M,N] = A[M,K] @ W[K,N]  (+bias, +res, +gelu per EPI)
// requires M%64==0, K%16==0 ; N guarded.
#define BM 64
#define BN 64
#define BK 16

template<int EPI>
__global__ __launch_bounds__(256) void gemm_kernel(const float* __restrict__ A, const float* __restrict__ W,
                                                   const float* __restrict__ bias, const float* __restrict__ res,
                                                   float* __restrict__ C, int M, int N, int K) {
  __shared__ __align__(16) float As[BK][BM];
  __shared__ __align__(16) float Wsh[BK][BN];
  int tid = threadIdx.x;
  int bm = blockIdx.y * BM;
  int bn = blockIdx.x * BN;
  float acc[4][4] = {};
  int ar = tid >> 2, ak = (tid & 3) << 2;
  int wk = tid >> 4, wn = (tid & 15) << 2;
  int tr = (tid >> 4) << 2;
  int tc = (tid & 15) << 2;
  for (int k0 = 0; k0 < K; k0 += BK) {
    float4 av = *(const float4*)(A + (size_t)(bm + ar) * K + k0 + ak);
    As[ak + 0][ar] = av.x; As[ak + 1][ar] = av.y; As[ak + 2][ar] = av.z; As[ak + 3][ar] = av.w;
    float4 wv;
    if (bn + wn + 3 < N) {
      wv = *(const float4*)(W + (size_t)(k0 + wk) * N + bn + wn);
    } else {
      wv.x = (bn + wn + 0 < N) ? W[(size_t)(k0 + wk) * N + bn + wn + 0] : 0.f;
      wv.y = (bn + wn + 1 < N) ? W[(size_t)(k0 + wk) * N + bn + wn + 1] : 0.f;
      wv.z = (bn + wn + 2 < N) ? W[(size_t)(k0 + wk) * N + bn + wn + 2] : 0.f;
      wv.w = (bn + wn + 3 < N) ? W[(size_t)(k0 + wk) * N + bn + wn + 3] : 0.f;
    }
    *(float4*)&Wsh[wk][wn] = wv;
    __syncthreads();
#pragma unroll
    for (int kk = 0; kk < BK; ++kk) {
      float4 a = *(const float4*)&As[kk][tr];
      float4 bb = *(const float4*)&Wsh[kk][tc];
      acc[0][0] += a.x * bb.x; acc[0][1] += a.x * bb.y; acc[0][2] += a.x * bb.z; acc[0][3] += a.x * bb.w;
      acc[1][0] += a.y * bb.x; acc[1][1] += a.y * bb.y; acc[1][2] += a.y * bb.z; acc[1][3] += a.y * bb.w;
      acc[2][0] += a.z * bb.x; acc[2][1] += a.z * bb.y; acc[2][2] += a.z * bb.z; acc[2][3] += a.z * bb.w;
      acc[3][0] += a.w * bb.x; acc[3][1] += a.w * bb.y; acc[3][2] += a.w * bb.z; acc[3][3] += a.w * bb.w;
    }
    __syncthreads();
  }
#pragma unroll
  for (int i = 0; i < 4; ++i) {
    int row = bm + tr + i;
#pragma unroll
    for (int j = 0; j < 4; ++j) {
      int col = bn + tc + j;
      if (col < N) {
        float v = acc[i][j];
        if (EPI >= 1) v += bias[col];
        if (EPI == 2) v += res[(size_t)row * N + col];
        if (EPI == 3) v = 0.5f * v * (1.0f + erff(v * 0.70710678118654752f));
        C[(size_t)row * N + col] = v;
      }
    }
  }
}

// ---------------------------------------------------------------- attention (fused per row)
__global__ __launch_bounds__(128) void attn_kernel(const float* __restrict__ Q, const float* __restrict__ K,
                                                   const float* __restrict__ V, const float* __restrict__ Mm,
                                                   float* __restrict__ O, int N) {
  int i = blockIdx.x, h = blockIdx.y, b = blockIdx.z;
  int tid = threadIdx.x;
  __shared__ float q[DH];
  __shared__ float s[ROI];
  __shared__ float red[128];
  const float* Qrow = Q + ((size_t)b * N + i) * (HEADS * DH) + h * DH;
  for (int d = tid; d < DH; d += 128) q[d] = Qrow[d];
  __syncthreads();
  const float* Kb = K + (size_t)b * N * (HEADS * DH) + h * DH;
  const float* Mrow = Mm + ((size_t)b * N + i) * N;
  for (int j = tid; j < N; j += 128) {
    const float* Kr = Kb + (size_t)j * (HEADS * DH);
    float acc = 0.f;
#pragma unroll 4
    for (int d = 0; d < DH; ++d) acc += q[d] * Kr[d];
    s[j] = acc * ATT_SCALE * (1.0f + Mrow[j]);
  }
  __syncthreads();
  float lm = -INFINITY;
  for (int j = tid; j < N; j += 128) lm = fmaxf(lm, s[j]);
  red[tid] = lm; __syncthreads();
  for (int st = 64; st > 0; st >>= 1) { if (tid < st) red[tid] = fmaxf(red[tid], red[tid + st]); __syncthreads(); }
  float mx = red[0];
  __syncthreads();
  float ls = 0.f;
  for (int j = tid; j < N; j += 128) { float e = expf(s[j] - mx); s[j] = e; ls += e; }
  red[tid] = ls; __syncthreads();
  for (int st = 64; st > 0; st >>= 1) { if (tid < st) red[tid] += red[tid + st]; __syncthreads(); }
  float inv = 1.0f / red[0];
  __syncthreads();
  const float* Vb = V + (size_t)b * N * (HEADS * DH) + h * DH;
  float* Orow = O + ((size_t)b * N + i) * (HEADS * DH) + h * DH;
  for (int d = tid; d < DH; d += 128) {
    float acc = 0.f;
    for (int j = 0; j < N; ++j) acc += s[j] * Vb[(size_t)j * (HEADS * DH) + d];
    Orow[d] = acc * inv;
  }
}

// ---------------------------------------------------------------- layernorm
__global__ __launch_bounds__(128) void ln_kernel(const float* __restrict__ Y, const float* __restrict__ g,
                                                 const float* __restrict__ bta, float* __restrict__ X) {
  int row = blockIdx.x;
  const float* y = Y + (size_t)row * ROI;
  float* x = X + (size_t)row * ROI;
  int tid = threadIdx.x;
  __shared__ float red[128];
  float s = 0.f;
  for (int c = tid; c < ROI; c += 128) s += y[c];
  red[tid] = s; __syncthreads();
  for (int st = 64; st > 0; st >>= 1) { if (tid < st) red[tid] += red[tid + st]; __syncthreads(); }
  float mu = red[0] / ROI;
  __syncthreads();
  float v = 0.f;
  for (int c = tid; c < ROI; c += 128) { float d = y[c] - mu; v += d * d; }
  red[tid] = v; __syncthreads();
  for (int st = 64; st > 0; st >>= 1) { if (tid < st) red[tid] += red[tid + st]; __syncthreads(); }
  float rstd = rsqrtf(red[0] / ROI + 1e-5f);
  for (int c = tid; c < ROI; c += 128) x[c] = (y[c] - mu) * rstd * g[c] + bta[c];
}

// ---------------------------------------------------------------- classifier head
__global__ __launch_bounds__(128) void cls_kernel(const float* __restrict__ X, const float* __restrict__ r1w,
                                                  const float* __restrict__ r1b, const float* __restrict__ r2w,
                                                  const float* __restrict__ r2b, float* __restrict__ probs, int N) {
  int b = blockIdx.x, tid = threadIdx.x;
  __shared__ float gf[ROI];
  __shared__ float hid[128];
  for (int c = tid; c < ROI; c += 128) {
    float s = 0.f;
    for (int n = 0; n < N; ++n) s += X[((size_t)b * N + n) * ROI + c];
    gf[c] = s / (float)N;
  }
  __syncthreads();
  {
    float a = r1b[tid];
    for (int k = 0; k < ROI; ++k) a += gf[k] * r1w[k * 128 + tid];
    hid[tid] = (a >= 0.f) ? a : 0.01f * a;
  }
  __syncthreads();
  if (tid < NC) {
    float l = r2b[tid];
    for (int k = 0; k < 128; ++k) l += hid[k] * r2w[k * NC + tid];
    gf[tid] = l;
  }
  __syncthreads();
  if (tid == 0) {
    float m = fmaxf(gf[0], gf[1]);
    float e0 = expf(gf[0] - m), e1 = expf(gf[1] - m);
    float inv = 1.f / (e0 + e1);
    probs[b * NC + 0] = e0 * inv;
    probs[b * NC + 1] = e1 * inv;
  }
}

// ---------------------------------------------------------------- pooling
__global__ __launch_bounds__(128) void score_kernel(const float* __restrict__ M, const float* __restrict__ X,
                                                    const float* __restrict__ pws, const float* __restrict__ pwf,
                                                    const float* __restrict__ pmw, const float* __restrict__ pmb,
                                                    float* __restrict__ scores) {
  int i = blockIdx.x, b = blockIdx.y, tid = threadIdx.x;
  const float* mr = M + ((size_t)b * ROI + i) * ROI;
  const float* xr = X + ((size_t)b * ROI + i) * ROI;
  float s1 = 0.f, s2 = 0.f;
  for (int j = tid; j < ROI; j += 128) { s1 += mr[j] * pws[j]; s2 += xr[j] * pwf[j]; }
  __shared__ float r1[128], r2[128];
  r1[tid] = s1; r2[tid] = s2; __syncthreads();
  for (int st = 64; st > 0; st >>= 1) {
    if (tid < st) { r1[tid] += r1[tid + st]; r2[tid] += r2[tid + st]; }
    __syncthreads();
  }
  if (tid == 0) {
    float a = fabsf(r1[0]), c = fabsf(r2[0]);
    float z = a * pmw[0] + c * pmw[1] + pmb[0];
    scores[b * ROI + i] = 1.f / (1.f + expf(-z));
  }
}

__global__ __launch_bounds__(128) void select_kernel(const float* __restrict__ scores, int* __restrict__ idx) {
  int b = blockIdx.x, tid = threadIdx.x;
  __shared__ float sc[ROI];
  __shared__ int sel[ROI];
  for (int i = tid; i < ROI; i += 128) sc[i] = scores[b * ROI + i];
  __syncthreads();
  for (int i = tid; i < ROI; i += 128) {
    float si = sc[i];
    int rank = 0;
    for (int j = 0; j < ROI; ++j) {
      float sj = sc[j];
      rank += (sj > si) || (sj == si && j < i);
    }
    sel[i] = (rank < KPOOL) ? 1 : 0;
  }
  __syncthreads();
  for (int i = tid; i < ROI; i += 128) {
    if (sel[i]) {
      int pos = 0;
      for (int j = 0; j < i; ++j) pos += sel[j];
      idx[b * KPOOL + pos] = i;
    }
  }
}

__global__ __launch_bounds__(128) void gatherx_kernel(const float* __restrict__ X, const float* __restrict__ scores,
                                                      const int* __restrict__ idx, float* __restrict__ Xp) {
  int p = blockIdx.x % KPOOL, b = blockIdx.x / KPOOL, tid = threadIdx.x;
  int src = idx[b * KPOOL + p];
  float sw = scores[b * ROI + src];
  const float* xr = X + ((size_t)b * ROI + src) * ROI;
  float* o = Xp + ((size_t)b * KPOOL + p) * ROI;
  for (int c = tid; c < ROI; c += 128) o[c] = xr[c] * sw;
}

__global__ __launch_bounds__(128) void gatherm_kernel(const float* __restrict__ M, const int* __restrict__ idx,
                                                      float* __restrict__ Mp) {
  int p = blockIdx.x % KPOOL, b = blockIdx.x / KPOOL, tid = threadIdx.x;
  __shared__ int id[KPOOL];
  for (int q = tid; q < KPOOL; q += 128) id[q] = idx[b * KPOOL + q];
  __syncthreads();
  int src = idx[b * KPOOL + p];
  const float* mr = M + ((size_t)b * ROI + src) * ROI;
  float* o = Mp + ((size_t)b * KPOOL + p) * KPOOL;
  for (int q = tid; q < KPOOL; q += 128) o[q] = mr[id[q]];
}

// ---------------------------------------------------------------- final output
__global__ __launch_bounds__(128) void final_kernel(const float* __restrict__ X, const float* __restrict__ probs,
                                                    float* __restrict__ out, int N) {
  int b = blockIdx.x, tid = threadIdx.x;
  __shared__ float f[ROI];
  __shared__ float red[128];
  for (int c = tid; c < ROI; c += 128) {
    float s = 0.f;
    for (int n = 0; n < N; ++n) s += X[((size_t)b * N + n) * ROI + c];
    f[c] = s / (float)N;
  }
  __syncthreads();
  float ls = 0.f;
  for (int c = tid; c < ROI; c += 128) ls += f[c] * f[c];
  red[tid] = ls; __syncthreads();
  for (int st = 64; st > 0; st >>= 1) { if (tid < st) red[tid] += red[tid + st]; __syncthreads(); }
  float inv = 1.f / fmaxf(sqrtf(red[0]), 1e-12f);
  for (int c = tid; c < ROI; c += 128) out[b * ROI + c] = f[c] * inv;
  if (tid < NC) out[NB * ROI + b * NC + tid] = 0.5f * (probs[b * NC + tid] + probs[NB * NC + b * NC + tid]);
}

// ---------------------------------------------------------------- host orchestration
static inline void gemm_launch0(const float* A, const float* W, float* C, int M, int N, int K, hipStream_t st) {
  dim3 g((N + BN - 1) / BN, M / BM);
  gemm_kernel<0><<<g, 256, 0, st>>>(A, W, nullptr, nullptr, C, M, N, K);
}
static inline void gemm_launch2(const float* A, const float* W, const float* bias, const float* res, float* C,
                                int M, int N, int K, hipStream_t st) {
  dim3 g((N + BN - 1) / BN, M / BM);
  gemm_kernel<2><<<g, 256, 0, st>>>(A, W, bias, res, C, M, N, K);
}
static inline void gemm_launch3(const float* A, const float* W, const float* bias, float* C,
                                int M, int N, int K, hipStream_t st) {
  dim3 g((N + BN - 1) / BN, M / BM);
  gemm_kernel<3><<<g, 256, 0, st>>>(A, W, bias, nullptr, C, M, N, K);
}

extern "C" void kernel_launch(void* const* d_in, const int* in_sizes, int n_in,
                              void* d_out, int out_size, void* d_ws, size_t ws_size,
                              hipStream_t stream) {
  const float* in  = (const float*)d_in[0];
  const float* sel = (const float*)d_in[1];
  const float* wq  = (const float*)d_in[2];
  const float* wk  = (const float*)d_in[3];
  const float* wv  = (const float*)d_in[4];
  const float* wo  = (const float*)d_in[5];
  const float* bo  = (const float*)d_in[6];
  const float* w1  = (const float*)d_in[7];
  const float* b1  = (const float*)d_in[8];
  const float* w2  = (const float*)d_in[9];
  const float* b2  = (const float*)d_in[10];
  const float* lng = (const float*)d_in[11];
  const float* lnb = (const float*)d_in[12];
  const float* pws = (const float*)d_in[13];
  const float* pwf = (const float*)d_in[14];
  const float* pmw = (const float*)d_in[15];
  const float* pmb = (const float*)d_in[16];
  const float* r1w = (const float*)d_in[17];
  const float* r1b = (const float*)d_in[18];
  const float* r2w = (const float*)d_in[19];
  const float* r2b = (const float*)d_in[20];
  float* out = (float*)d_out;

  float* ws = (float*)d_ws;
  const size_t AT = (size_t)NB * ROI * ROI;  // 10,240,000 floats
  float* A0 = ws;
  float* A1 = ws + AT;
  float* A2 = ws + 2 * AT;
  float* A3 = ws + 3 * AT;
  float* A4 = ws + 4 * AT;
  float* A5 = ws + 5 * AT;
  float* smalls = ws + 6 * AT;
  float* meanb = smalls;                 // 64
  float* stdb  = smalls + 64;            // 64
  float* scores = smalls + 128;          // 64*400
  int*   idx = (int*)(smalls + 128 + NB * ROI);       // 64*280 ints
  float* probs = smalls + 128 + NB * ROI + NB * KPOOL; // 2*64*2

  pre_reduce_kernel<<<NB, 256, 0, stream>>>(in, meanb, stdb);
  {
    size_t tot = AT;
    build_xm_kernel<<<(int)((tot + 255) / 256), 256, 0, stream>>>(in, sel, meanb, stdb, A0, A1);
  }

  // ---------------- depth 0: N=400, x=A0, m=A1
  {
    const int N = ROI;
    const int Mtok = NB * N;  // 25600
    const float* x = A0;
    const float* m = A1;
    float* Q = A2; float* Kb = A3; float* Vb = A4; float* O = A5;
    gemm_launch0(x, wq + 0, Q,  Mtok, ROI, ROI, stream);
    gemm_launch0(x, wk + 0, Kb, Mtok, ROI, ROI, stream);
    gemm_launch0(x, wv + 0, Vb, Mtok, ROI, ROI, stream);
    attn_kernel<<<dim3(N, HEADS, NB), 128, 0, stream>>>(Q, Kb, Vb, m, O, N);
    float* Xa = A2;  // over Q
    gemm_launch2(O, wo + 0, bo + 0, x, Xa, Mtok, ROI, ROI, stream);
    float* H = A3;   // spans A3+A4
    gemm_launch3(Xa, w1 + 0, b1 + 0, H, Mtok, HIDF, ROI, stream);
    float* Y = A5;   // over O
    gemm_launch2(H, w2 + 0, b2 + 0, Xa, Y, Mtok, ROI, HIDF, stream);
    float* Xn = A0;  // over x
    ln_kernel<<<Mtok, 128, 0, stream>>>(Y, lng + 0, lnb + 0, Xn);
    cls_kernel<<<NB, 128, 0, stream>>>(Xn, r1w + 0, r1b + 0, r2w + 0, r2b + 0, probs, N);
    // pooling
    score_kernel<<<dim3(ROI, NB), 128, 0, stream>>>(m, Xn, pws, pwf, pmw, pmb, scores);
    select_kernel<<<NB, 128, 0, stream>>>(scores, idx);
    gatherx_kernel<<<NB * KPOOL, 128, 0, stream>>>(Xn, scores, idx, A5);  // Xp -> A5
    gatherm_kernel<<<NB * KPOOL, 128, 0, stream>>>(m, idx, A2);            // Mp -> A2
  }

  // ---------------- depth 1: N=280, x=A5, m=A2
  {
    const int N = KPOOL;
    const int Mtok = NB * N;  // 17920
    const float* x = A5;
    const float* m = A2;
    const int d = 1;
    const float* wq1 = wq + (size_t)d * ROI * ROI;
    const float* wk1 = wk + (size_t)d * ROI * ROI;
    const float* wv1 = wv + (size_t)d * ROI * ROI;
    const float* wo1 = wo + (size_t)d * ROI * ROI;
    const float* bo1 = bo + (size_t)d * ROI;
    const float* w11 = w1 + (size_t)d * ROI * HIDF;
    const float* b11 = b1 + (size_t)d * HIDF;
    const float* w21 = w2 + (size_t)d * HIDF * ROI;
    const float* b21 = b2 + (size_t)d * ROI;
    const float* lng1 = lng + (size_t)d * ROI;
    const float* lnb1 = lnb + (size_t)d * ROI;
    const float* r1w1 = r1w + (size_t)d * ROI * 128;
    const float* r1b1 = r1b + (size_t)d * 128;
    const float* r2w1 = r2w + (size_t)d * 128 * NC;
    const float* r2b1 = r2b + (size_t)d * NC;

    float* Q = A0; float* Kb = A1; float* Vb = A3; float* O = A4;
    gemm_launch0(x, wq1, Q,  Mtok, ROI, ROI, stream);
    gemm_launch0(x, wk1, Kb, Mtok, ROI, ROI, stream);
    gemm_launch0(x, wv1, Vb, Mtok, ROI, ROI, stream);
    attn_kernel<<<dim3(N, HEADS, NB), 128, 0, stream>>>(Q, Kb, Vb, m, O, N);
    float* Xa = A0;  // over Q
    gemm_launch2(O, wo1, bo1, x, Xa, Mtok, ROI, ROI, stream);
    float* H = A3;   // spans into A4 (both dead)
    gemm_launch3(Xa, w11, b11, H, Mtok, HIDF, ROI, stream);
    float* Y = A1;   // over Kb
    gemm_launch2(H, w21, b21, Xa, Y, Mtok, ROI, HIDF, stream);
    float* Xf = A2;  // over m (dead after attention)
    ln_kernel<<<Mtok, 128, 0, stream>>>(Y, lng1, lnb1, Xf);
    cls_kernel<<<NB, 128, 0, stream>>>(Xf, r1w1, r1b1, r2w1, r2b1, probs + NB * NC, N);
    final_kernel<<<NB, 128, 0, stream>>>(Xf, probs, out, N);
  }
  (void)in_sizes; (void)n_in; (void)out_size; (void)ws_size;
}

// Round 2
// 3657.344 us; speedup vs baseline: 2.6081x; 2.6081x over previous
//
#include <hip/hip_runtime.h>
#include <math.h>

#define ROI 400
#define HEADS 4
#define DH 100
#define NB 64
#define HIDF 800
#define NC 2
#define KPOOL 280
#define ATT_SCALE 0.1f

// ---------------------------------------------------------------- preprocess
__global__ __launch_bounds__(256) void pre_reduce_kernel(const float* __restrict__ in,
                                                         float* __restrict__ meanb,
                                                         float* __restrict__ stdb) {
  int b = blockIdx.x;
  const float* p = in + (size_t)b * ROI * (2 * ROI);
  double s = 0.0, ss = 0.0;
  const int n = ROI * ROI;
  for (int e = threadIdx.x; e < n; e += blockDim.x) {
    int r = e / ROI, c = e % ROI;
    float v = log10f(p[(size_t)r * (2 * ROI) + ROI + c] + 1.0f);
    s += v; ss += (double)v * (double)v;
  }
  __shared__ double rs[256], rss[256];
  rs[threadIdx.x] = s; rss[threadIdx.x] = ss;
  __syncthreads();
  for (int st = 128; st > 0; st >>= 1) {
    if (threadIdx.x < st) { rs[threadIdx.x] += rs[threadIdx.x + st]; rss[threadIdx.x] += rss[threadIdx.x + st]; }
    __syncthreads();
  }
  if (threadIdx.x == 0) {
    double mean = rs[0] / n;
    double var = (rss[0] - rs[0] * rs[0] / n) / (double)(n - 1);
    meanb[b] = (float)mean;
    stdb[b]  = (float)(sqrt(var) + 1e-6);
  }
}

__global__ __launch_bounds__(256) void build_xm_kernel(const float* __restrict__ in,
                                                       const float* __restrict__ sel,
                                                       const float* __restrict__ meanb,
                                                       const float* __restrict__ stdb,
                                                       float* __restrict__ X, float* __restrict__ M) {
  size_t e = (size_t)blockIdx.x * blockDim.x + threadIdx.x;
  const size_t total = (size_t)NB * ROI * ROI;
  if (e >= total) return;
  int c = (int)(e % ROI);
  int r = (int)((e / ROI) % ROI);
  int b = (int)(e / ((size_t)ROI * ROI));
  const float* row = in + ((size_t)b * ROI + r) * (2 * ROI);
  X[e] = row[c];
  float v = log10f(row[ROI + c] + 1.0f);
  float sg = 1.0f / (1.0f + expf(-sel[r * ROI + c]));
  M[e] = ((v - meanb[b]) / stdb[b]) * sg;
}

// ---------------------------------------------------------------- GEMM
#define BM 64
#define BN 64
#define BK 16

template<int EPI>
__global__ __launch_bounds__(256) void gemm_kernel(const float* __restrict__ A, const float* __restrict__ W,
                                                   const float* __restrict__ bias, const float* __restrict__ res,
                                                   float* __restrict__ C, int M, int N, int K) {
  __shared__ __align__(16) float As[BK][BM];
  __shared__ __align__(16) float Wsh[BK][BN];
  int tid = threadIdx.x;
  int bm = blockIdx.y * BM;
  int bn = blockIdx.x * BN;
  float acc[4][4] = {};
  int ar = tid >> 2, ak = (tid & 3) << 2;
  int wk = tid >> 4, wn = (tid & 15) << 2;
  int tr = (tid >> 4) << 2;
  int tc = (tid & 15) << 2;
  for (int k0 = 0; k0 < K; k0 += BK) {
    float4 av = *(const float4*)(A + (size_t)(bm + ar) * K + k0 + ak);
    As[ak + 0][ar] = av.x; As[ak + 1][ar] = av.y; As[ak + 2][ar] = av.z; As[ak + 3][ar] = av.w;
    float4 wv;
    if (bn + wn + 3 < N) {
      wv = *(const float4*)(W + (size_t)(k0 + wk) * N + bn + wn);
    } else {
      wv.x = (bn + wn + 0 < N) ? W[(size_t)(k0 + wk) * N + bn + wn + 0] : 0.f;
      wv.y = (bn + wn + 1 < N) ? W[(size_t)(k0 + wk) * N + bn + wn + 1] : 0.f;
      wv.z = (bn + wn + 2 < N) ? W[(size_t)(k0 + wk) * N + bn + wn + 2] : 0.f;
      wv.w = (bn + wn + 3 < N) ? W[(size_t)(k0 + wk) * N + bn + wn + 3] : 0.f;
    }
    *(float4*)&Wsh[wk][wn] = wv;
    __syncthreads();
#pragma unroll
    for (int kk = 0; kk < BK; ++kk) {
      float4 a = *(const float4*)&As[kk][tr];
      float4 bb = *(const float4*)&Wsh[kk][tc];
      acc[0][0] += a.x * bb.x; acc[0][1] += a.x * bb.y; acc[0][2] += a.x * bb.z; acc[0][3] += a.x * bb.w;
      acc[1][0] += a.y * bb.x; acc[1][1] += a.y * bb.y; acc[1][2] += a.y * bb.z; acc[1][3] += a.y * bb.w;
      acc[2][0] += a.z * bb.x; acc[2][1] += a.z * bb.y; acc[2][2] += a.z * bb.z; acc[2][3] += a.z * bb.w;
      acc[3][0] += a.w * bb.x; acc[3][1] += a.w * bb.y; acc[3][2] += a.w * bb.z; acc[3][3] += a.w * bb.w;
    }
    __syncthreads();
  }
#pragma unroll
  for (int i = 0; i < 4; ++i) {
    int row = bm + tr + i;
#pragma unroll
    for (int j = 0; j < 4; ++j) {
      int col = bn + tc + j;
      if (col < N) {
        float v = acc[i][j];
        if (EPI >= 1) v += bias[col];
        if (EPI == 2) v += res[(size_t)row * N + col];
        if (EPI == 3) v = 0.5f * v * (1.0f + erff(v * 0.70710678118654752f));
        C[(size_t)row * N + col] = v;
      }
    }
  }
}

// ---------------------------------------------------------------- fused flash attention
// block = 256 threads, handles 64 query rows of one (b, h). Tiles over 64 keys.
#define BI 64
#define BJ 64

__global__ __launch_bounds__(256) void fattn_kernel(const float* __restrict__ Q, const float* __restrict__ K,
                                                    const float* __restrict__ V, const float* __restrict__ Mm,
                                                    float* __restrict__ O, int N) {
  __shared__ __align__(16) float Qst[DH][BI];    // Q tile transposed [d][row]  25.6 KB
  __shared__ __align__(16) float KV[BJ * 128];   // union: Kst[DH][BJ] / Vs[BJ][128]  32.8 KB
  __shared__ __align__(16) float Ss[BI][68];     // P tile  17.4 KB
  float (*Kst)[BJ] = (float (*)[BJ])KV;
  float (*Vs)[128] = (float (*)[128])KV;

  const int tid = threadIdx.x;
  const int tr = tid >> 4;   // 0..15 -> rows 4tr..4tr+3
  const int tc = tid & 15;   // 0..15
  const int i0 = blockIdx.x * BI;
  const int h  = blockIdx.y;
  const int b  = blockIdx.z;
  const int HD = HEADS * DH;  // 400

  const float* Qb = Q + (size_t)b * N * HD + h * DH;
  const float* Kb = K + (size_t)b * N * HD + h * DH;
  const float* Vb = V + (size_t)b * N * HD + h * DH;

  // stage Q transposed (once). lanes of a wave share c -> LDS writes conflict-free.
  for (int e = tid; e < (DH / 4) * BI; e += 256) {
    int c = e >> 6, r = e & 63;
    int gi = i0 + r; if (gi >= N) gi = N - 1;
    float4 v = *(const float4*)(Qb + (size_t)gi * HD + 4 * c);
    Qst[4 * c + 0][r] = v.x; Qst[4 * c + 1][r] = v.y;
    Qst[4 * c + 2][r] = v.z; Qst[4 * c + 3][r] = v.w;
  }

  float m_i[4], l_i[4];
  float oa[4][4] = {};
  float ob[4][4] = {};
#pragma unroll
  for (int i = 0; i < 4; ++i) { m_i[i] = -INFINITY; l_i[i] = 0.f; }

  const int njt = (N + BJ - 1) / BJ;
  for (int jt = 0; jt < njt; ++jt) {
    const int j0 = jt * BJ;
    __syncthreads();   // previous PV done with Vs (union with Kst); Qst staged
    for (int e = tid; e < (DH / 4) * BJ; e += 256) {
      int c = e >> 6, r = e & 63;
      int gj = j0 + r; if (gj >= N) gj = N - 1;
      float4 v = *(const float4*)(Kb + (size_t)gj * HD + 4 * c);
      Kst[4 * c + 0][r] = v.x; Kst[4 * c + 1][r] = v.y;
      Kst[4 * c + 2][r] = v.z; Kst[4 * c + 3][r] = v.w;
    }
    __syncthreads();

    // S tile: 64x64x100, 4x4 per thread
    float sacc[4][4] = {};
#pragma unroll 4
    for (int kk = 0; kk < DH; ++kk) {
      float4 a  = *(const float4*)&Qst[kk][4 * tr];
      float4 bb = *(const float4*)&Kst[kk][4 * tc];
      sacc[0][0] += a.x * bb.x; sacc[0][1] += a.x * bb.y; sacc[0][2] += a.x * bb.z; sacc[0][3] += a.x * bb.w;
      sacc[1][0] += a.y * bb.x; sacc[1][1] += a.y * bb.y; sacc[1][2] += a.y * bb.z; sacc[1][3] += a.y * bb.w;
      sacc[2][0] += a.z * bb.x; sacc[2][1] += a.z * bb.y; sacc[2][2] += a.z * bb.z; sacc[2][3] += a.z * bb.w;
      sacc[3][0] += a.w * bb.x; sacc[3][1] += a.w * bb.y; sacc[3][2] += a.w * bb.z; sacc[3][3] += a.w * bb.w;
    }

    // epilogue: scale * (1+M), mask, online softmax over 16-lane row groups
    const float* Mbase = Mm + (size_t)b * N * N;
#pragma unroll
    for (int i = 0; i < 4; ++i) {
      int gi = i0 + 4 * tr + i; if (gi >= N) gi = N - 1;
      const float* Mr = Mbase + (size_t)gi * N + j0 + 4 * tc;
      float mv[4];
      if (j0 + 4 * tc + 3 < N) {
        float4 m4 = *(const float4*)Mr;
        mv[0] = m4.x; mv[1] = m4.y; mv[2] = m4.z; mv[3] = m4.w;
      } else {
#pragma unroll
        for (int q = 0; q < 4; ++q) mv[q] = (j0 + 4 * tc + q < N) ? Mr[q] : 0.f;
      }
      float p[4];
      float rm = -INFINITY;
#pragma unroll
      for (int q = 0; q < 4; ++q) {
        float s = (j0 + 4 * tc + q < N) ? sacc[i][q] * ATT_SCALE * (1.0f + mv[q]) : -INFINITY;
        p[q] = s;
        rm = fmaxf(rm, s);
      }
      rm = fmaxf(rm, __shfl_xor(rm, 1, 16));
      rm = fmaxf(rm, __shfl_xor(rm, 2, 16));
      rm = fmaxf(rm, __shfl_xor(rm, 4, 16));
      rm = fmaxf(rm, __shfl_xor(rm, 8, 16));
      float nm = fmaxf(m_i[i], rm);
      float f = expf(m_i[i] - nm);
      float ts = 0.f;
#pragma unroll
      for (int q = 0; q < 4; ++q) { float e = expf(p[q] - nm); p[q] = e; ts += e; }
      ts += __shfl_xor(ts, 1, 16);
      ts += __shfl_xor(ts, 2, 16);
      ts += __shfl_xor(ts, 4, 16);
      ts += __shfl_xor(ts, 8, 16);
      l_i[i] = l_i[i] * f + ts;
      m_i[i] = nm;
#pragma unroll
      for (int q = 0; q < 4; ++q) { oa[i][q] *= f; ob[i][q] *= f; }
      *(float4*)&Ss[4 * tr + i][4 * tc] = make_float4(p[0], p[1], p[2], p[3]);
    }
    __syncthreads();   // Ss ready; Kst reads done -> reuse as Vs

    for (int e = tid; e < (DH / 4) * BJ; e += 256) {
      int c = e % 25, r = e / 25;
      int gj = j0 + r; if (gj >= N) gj = N - 1;
      *(float4*)&Vs[r][4 * c] = *(const float4*)(Vb + (size_t)gj * HD + 4 * c);
    }
    __syncthreads();

    // PV: out[4 rows][d in {4tc..}+{64+4tc..}] += P * V
#pragma unroll 2
    for (int jj = 0; jj < BJ / 4; ++jj) {
      float4 p0 = *(const float4*)&Ss[4 * tr + 0][4 * jj];
      float4 p1 = *(const float4*)&Ss[4 * tr + 1][4 * jj];
      float4 p2 = *(const float4*)&Ss[4 * tr + 2][4 * jj];
      float4 p3 = *(const float4*)&Ss[4 * tr + 3][4 * jj];
      float pv[4][4] = {{p0.x, p0.y, p0.z, p0.w}, {p1.x, p1.y, p1.z, p1.w},
                        {p2.x, p2.y, p2.z, p2.w}, {p3.x, p3.y, p3.z, p3.w}};
#pragma unroll
      for (int q = 0; q < 4; ++q) {
        int j = 4 * jj + q;
        float4 va = *(const float4*)&Vs[j][4 * tc];
        float4 vb = *(const float4*)&Vs[j][64 + 4 * tc];  // cols >=100 are garbage, never stored
#pragma unroll
        for (int i = 0; i < 4; ++i) {
          oa[i][0] += pv[i][q] * va.x; oa[i][1] += pv[i][q] * va.y;
          oa[i][2] += pv[i][q] * va.z; oa[i][3] += pv[i][q] * va.w;
          ob[i][0] += pv[i][q] * vb.x; ob[i][1] += pv[i][q] * vb.y;
          ob[i][2] += pv[i][q] * vb.z; ob[i][3] += pv[i][q] * vb.w;
        }
      }
    }
  }

  float* Ob = O + (size_t)b * N * HD + h * DH;
#pragma unroll
  for (int i = 0; i < 4; ++i) {
    int gi = i0 + 4 * tr + i;
    if (gi < N) {
      float inv = 1.0f / l_i[i];
      float4 w = make_float4(oa[i][0] * inv, oa[i][1] * inv, oa[i][2] * inv, oa[i][3] * inv);
      *(float4*)(Ob + (size_t)gi * HD + 4 * tc) = w;
      if (tc < 9) {
        float4 w2 = make_float4(ob[i][0] * inv, ob[i][1] * inv, ob[i][2] * inv, ob[i][3] * inv);
        *(float4*)(Ob + (size_t)gi * HD + 64 + 4 * tc) = w2;
      }
    }
  }
}

// ---------------------------------------------------------------- layernorm
__global__ __launch_bounds__(128) void ln_kernel(const float* __restrict__ Y, const float* __restrict__ g,
                                                 const float* __restrict__ bta, float* __restrict__ X) {
  int row = blockIdx.x;
  const float* y = Y + (size_t)row * ROI;
  float* x = X + (size_t)row * ROI;
  int tid = threadIdx.x;
  __shared__ float red[128];
  float s = 0.f;
  for (int c = tid; c < ROI; c += 128) s += y[c];
  red[tid] = s; __syncthreads();
  for (int st = 64; st > 0; st >>= 1) { if (tid < st) red[tid] += red[tid + st]; __syncthreads(); }
  float mu = red[0] / ROI;
  __syncthreads();
  float v = 0.f;
  for (int c = tid; c < ROI; c += 128) { float d = y[c] - mu; v += d * d; }
  red[tid] = v; __syncthreads();
  for (int st = 64; st > 0; st >>= 1) { if (tid < st) red[tid] += red[tid + st]; __syncthreads(); }
  float rstd = rsqrtf(red[0] / ROI + 1e-5f);
  for (int c = tid; c < ROI; c += 128) x[c] = (y[c] - mu) * rstd * g[c] + bta[c];
}

// ---------------------------------------------------------------- classifier head
__global__ __launch_bounds__(128) void cls_kernel(const float* __restrict__ X, const float* __restrict__ r1w,
                                                  const float* __restrict__ r1b, const float* __restrict__ r2w,
                                                  const float* __restrict__ r2b, float* __restrict__ probs, int N) {
  int b = blockIdx.x, tid = threadIdx.x;
  __shared__ float gf[ROI];
  __shared__ float hid[128];
  for (int c = tid; c < ROI; c += 128) {
    float s = 0.f;
    for (int n = 0; n < N; ++n) s += X[((size_t)b * N + n) * ROI + c];
    gf[c] = s / (float)N;
  }
  __syncthreads();
  {
    float a = r1b[tid];
    for (int k = 0; k < ROI; ++k) a += gf[k] * r1w[k * 128 + tid];
    hid[tid] = (a >= 0.f) ? a : 0.01f * a;
  }
  __syncthreads();
  if (tid < NC) {
    float l = r2b[tid];
    for (int k = 0; k < 128; ++k) l += hid[k] * r2w[k * NC + tid];
    gf[tid] = l;
  }
  __syncthreads();
  if (tid == 0) {
    float m = fmaxf(gf[0], gf[1]);
    float e0 = expf(gf[0] - m), e1 = expf(gf[1] - m);
    float inv = 1.f / (e0 + e1);
    probs[b * NC + 0] = e0 * inv;
    probs[b * NC + 1] = e1 * inv;
  }
}

// ---------------------------------------------------------------- pooling
__global__ __launch_bounds__(128) void score_kernel(const float* __restrict__ M, const float* __restrict__ X,
                                                    const float* __restrict__ pws, const float* __restrict__ pwf,
                                                    const float* __restrict__ pmw, const float* __restrict__ pmb,
                                                    float* __restrict__ scores) {
  int i = blockIdx.x, b = blockIdx.y, tid = threadIdx.x;
  const float* mr = M + ((size_t)b * ROI + i) * ROI;
  const float* xr = X + ((size_t)b * ROI + i) * ROI;
  float s1 = 0.f, s2 = 0.f;
  for (int j = tid; j < ROI; j += 128) { s1 += mr[j] * pws[j]; s2 += xr[j] * pwf[j]; }
  __shared__ float r1[128], r2[128];
  r1[tid] = s1; r2[tid] = s2; __syncthreads();
  for (int st = 64; st > 0; st >>= 1) {
    if (tid < st) { r1[tid] += r1[tid + st]; r2[tid] += r2[tid + st]; }
    __syncthreads();
  }
  if (tid == 0) {
    float a = fabsf(r1[0]), c = fabsf(r2[0]);
    float z = a * pmw[0] + c * pmw[1] + pmb[0];
    scores[b * ROI + i] = 1.f / (1.f + expf(-z));
  }
}

__global__ __launch_bounds__(128) void select_kernel(const float* __restrict__ scores, int* __restrict__ idx) {
  int b = blockIdx.x, tid = threadIdx.x;
  __shared__ float sc[ROI];
  __shared__ int sel[ROI];
  for (int i = tid; i < ROI; i += 128) sc[i] = scores[b * ROI + i];
  __syncthreads();
  for (int i = tid; i < ROI; i += 128) {
    float si = sc[i];
    int rank = 0;
    for (int j = 0; j < ROI; ++j) {
      float sj = sc[j];
      rank += (sj > si) || (sj == si && j < i);
    }
    sel[i] = (rank < KPOOL) ? 1 : 0;
  }
  __syncthreads();
  for (int i = tid; i < ROI; i += 128) {
    if (sel[i]) {
      int pos = 0;
      for (int j = 0; j < i; ++j) pos += sel[j];
      idx[b * KPOOL + pos] = i;
    }
  }
}

__global__ __launch_bounds__(128) void gatherx_kernel(const float* __restrict__ X, const float* __restrict__ scores,
                                                      const int* __restrict__ idx, float* __restrict__ Xp) {
  int p = blockIdx.x % KPOOL, b = blockIdx.x / KPOOL, tid = threadIdx.x;
  int src = idx[b * KPOOL + p];
  float sw = scores[b * ROI + src];
  const float* xr = X + ((size_t)b * ROI + src) * ROI;
  float* o = Xp + ((size_t)b * KPOOL + p) * ROI;
  for (int c = tid; c < ROI; c += 128) o[c] = xr[c] * sw;
}

__global__ __launch_bounds__(128) void gatherm_kernel(const float* __restrict__ M, const int* __restrict__ idx,
                                                      float* __restrict__ Mp) {
  int p = blockIdx.x % KPOOL, b = blockIdx.x / KPOOL, tid = threadIdx.x;
  __shared__ int id[KPOOL];
  for (int q = tid; q < KPOOL; q += 128) id[q] = idx[b * KPOOL + q];
  __syncthreads();
  int src = idx[b * KPOOL + p];
  const float* mr = M + ((size_t)b * ROI + src) * ROI;
  float* o = Mp + ((size_t)b * KPOOL + p) * KPOOL;
  for (int q = tid; q < KPOOL; q += 128) o[q] = mr[id[q]];
}

// ---------------------------------------------------------------- final output
__global__ __launch_bounds__(128) void final_kernel(const float* __restrict__ X, const float* __restrict__ probs,
                                                    float* __restrict__ out, int N) {
  int b = blockIdx.x, tid = threadIdx.x;
  __shared__ float f[ROI];
  __shared__ float red[128];
  for (int c = tid; c < ROI; c += 128) {
    float s = 0.f;
    for (int n = 0; n < N; ++n) s += X[((size_t)b * N + n) * ROI + c];
    f[c] = s / (float)N;
  }
  __syncthreads();
  float ls = 0.f;
  for (int c = tid; c < ROI; c += 128) ls += f[c] * f[c];
  red[tid] = ls; __syncthreads();
  for (int st = 64; st > 0; st >>= 1) { if (tid < st) red[tid] += red[tid + st]; __syncthreads(); }
  float inv = 1.f / fmaxf(sqrtf(red[0]), 1e-12f);
  for (int c = tid; c < ROI; c += 128) out[b * ROI + c] = f[c] * inv;
  if (tid < NC) out[NB * ROI + b * NC + tid] = 0.5f * (probs[b * NC + tid] + probs[NB * NC + b * NC + tid]);
}

// ---------------------------------------------------------------- host orchestration
static inline void gemm_launch0(const float* A, const float* W, float* C, int M, int N, int K, hipStream_t st) {
  dim3 g((N + BN - 1) / BN, M / BM);
  gemm_kernel<0><<<g, 256, 0, st>>>(A, W, nullptr, nullptr, C, M, N, K);
}
static inline void gemm_launch2(const float* A, const float* W, const float* bias, const float* res, float* C,
                                int M, int N, int K, hipStream_t st) {
  dim3 g((N + BN - 1) / BN, M / BM);
  gemm_kernel<2><<<g, 256, 0, st>>>(A, W, bias, res, C, M, N, K);
}
static inline void gemm_launch3(const float* A, const float* W, const float* bias, float* C,
                                int M, int N, int K, hipStream_t st) {
  dim3 g((N + BN - 1) / BN, M / BM);
  gemm_kernel<3><<<g, 256, 0, st>>>(A, W, bias, nullptr, C, M, N, K);
}

extern "C" void kernel_launch(void* const* d_in, const int* in_sizes, int n_in,
                              void* d_out, int out_size, void* d_ws, size_t ws_size,
                              hipStream_t stream) {
  const float* in  = (const float*)d_in[0];
  const float* sel = (const float*)d_in[1];
  const float* wq  = (const float*)d_in[2];
  const float* wk  = (const float*)d_in[3];
  const float* wv  = (const float*)d_in[4];
  const float* wo  = (const float*)d_in[5];
  const float* bo  = (const float*)d_in[6];
  const float* w1  = (const float*)d_in[7];
  const float* b1  = (const float*)d_in[8];
  const float* w2  = (const float*)d_in[9];
  const float* b2  = (const float*)d_in[10];
  const float* lng = (const float*)d_in[11];
  const float* lnb = (const float*)d_in[12];
  const float* pws = (const float*)d_in[13];
  const float* pwf = (const float*)d_in[14];
  const float* pmw = (const float*)d_in[15];
  const float* pmb = (const float*)d_in[16];
  const float* r1w = (const float*)d_in[17];
  const float* r1b = (const float*)d_in[18];
  const float* r2w = (const float*)d_in[19];
  const float* r2b = (const float*)d_in[20];
  float* out = (float*)d_out;

  float* ws = (float*)d_ws;
  const size_t AT = (size_t)NB * ROI * ROI;  // 10,240,000 floats
  float* A0 = ws;
  float* A1 = ws + AT;
  float* A2 = ws + 2 * AT;
  float* A3 = ws + 3 * AT;
  float* A4 = ws + 4 * AT;
  float* A5 = ws + 5 * AT;
  float* smalls = ws + 6 * AT;
  float* meanb = smalls;                 // 64
  float* stdb  = smalls + 64;            // 64
  float* scores = smalls + 128;          // 64*400
  int*   idx = (int*)(smalls + 128 + NB * ROI);       // 64*280 ints
  float* probs = smalls + 128 + NB * ROI + NB * KPOOL; // 2*64*2

  pre_reduce_kernel<<<NB, 256, 0, stream>>>(in, meanb, stdb);
  {
    size_t tot = AT;
    build_xm_kernel<<<(int)((tot + 255) / 256), 256, 0, stream>>>(in, sel, meanb, stdb, A0, A1);
  }

  // ---------------- depth 0: N=400, x=A0, m=A1
  {
    const int N = ROI;
    const int Mtok = NB * N;  // 25600
    const float* x = A0;
    const float* m = A1;
    float* Q = A2; float* Kb = A3; float* Vb = A4; float* O = A5;
    gemm_launch0(x, wq + 0, Q,  Mtok, ROI, ROI, stream);
    gemm_launch0(x, wk + 0, Kb, Mtok, ROI, ROI, stream);
    gemm_launch0(x, wv + 0, Vb, Mtok, ROI, ROI, stream);
    fattn_kernel<<<dim3((N + BI - 1) / BI, HEADS, NB), 256, 0, stream>>>(Q, Kb, Vb, m, O, N);
    float* Xa = A2;  // over Q
    gemm_launch2(O, wo + 0, bo + 0, x, Xa, Mtok, ROI, ROI, stream);
    float* H = A3;   // spans A3+A4
    gemm_launch3(Xa, w1 + 0, b1 + 0, H, Mtok, HIDF, ROI, stream);
    float* Y = A5;   // over O
    gemm_launch2(H, w2 + 0, b2 + 0, Xa, Y, Mtok, ROI, HIDF, stream);
    float* Xn = A0;  // over x
    ln_kernel<<<Mtok, 128, 0, stream>>>(Y, lng + 0, lnb + 0, Xn);
    cls_kernel<<<NB, 128, 0, stream>>>(Xn, r1w + 0, r1b + 0, r2w + 0, r2b + 0, probs, N);
    score_kernel<<<dim3(ROI, NB), 128, 0, stream>>>(m, Xn, pws, pwf, pmw, pmb, scores);
    select_kernel<<<NB, 128, 0, stream>>>(scores, idx);
    gatherx_kernel<<<NB * KPOOL, 128, 0, stream>>>(Xn, scores, idx, A5);  // Xp -> A5
    gatherm_kernel<<<NB * KPOOL, 128, 0, stream>>>(m, idx, A2);            // Mp -> A2
  }

  // ---------------- depth 1: N=280, x=A5, m=A2
  {
    const int N = KPOOL;
    const int Mtok = NB * N;  // 17920
    const float* x = A5;
    const float* m = A2;
    const int d = 1;
    const float* wq1 = wq + (size_t)d * ROI * ROI;
    const float* wk1 = wk + (size_t)d * ROI * ROI;
    const float* wv1 = wv + (size_t)d * ROI * ROI;
    const float* wo1 = wo + (size_t)d * ROI * ROI;
    const float* bo1 = bo + (size_t)d * ROI;
    const float* w11 = w1 + (size_t)d * ROI * HIDF;
    const float* b11 = b1 + (size_t)d * HIDF;
    const float* w21 = w2 + (size_t)d * HIDF * ROI;
    const float* b21 = b2 + (size_t)d * ROI;
    const float* lng1 = lng + (size_t)d * ROI;
    const float* lnb1 = lnb + (size_t)d * ROI;
    const float* r1w1 = r1w + (size_t)d * ROI * 128;
    const float* r1b1 = r1b + (size_t)d * 128;
    const float* r2w1 = r2w + (size_t)d * 128 * NC;
    const float* r2b1 = r2b + (size_t)d * NC;

    float* Q = A0; float* Kb = A1; float* Vb = A3; float* O = A4;
    gemm_launch0(x, wq1, Q,  Mtok, ROI, ROI, stream);
    gemm_launch0(x, wk1, Kb, Mtok, ROI, ROI, stream);
    gemm_launch0(x, wv1, Vb, Mtok, ROI, ROI, stream);
    fattn_kernel<<<dim3((N + BI - 1) / BI, HEADS, NB), 256, 0, stream>>>(Q, Kb, Vb, m, O, N);
    float* Xa = A0;  // over Q
    gemm_launch2(O, wo1, bo1, x, Xa, Mtok, ROI, ROI, stream);
    float* H = A3;   // spans into A4 (both dead)
    gemm_launch3(Xa, w11, b11, H, Mtok, HIDF, ROI, stream);
    float* Y = A1;   // over Kb
    gemm_launch2(H, w21, b21, Xa, Y, Mtok, ROI, HIDF, stream);
    float* Xf = A2;  // over m (dead after attention)
    ln_kernel<<<Mtok, 128, 0, stream>>>(Y, lng1, lnb1, Xf);
    cls_kernel<<<NB, 128, 0, stream>>>(Xf, r1w1, r1b1, r2w1, r2b1, probs + NB * NC, N);
    final_kernel<<<NB, 128, 0, stream>>>(Xf, probs, out, N);
  }
  (void)in_sizes; (void)n_in; (void)out_size; (void)ws_size;
}

// Round 3
// 3543.626 us; speedup vs baseline: 2.6918x; 1.0321x over previous
//
#include <hip/hip_runtime.h>
#include <math.h>

#define ROI 400
#define HEADS 4
#define DH 100
#define NB 64
#define HIDF 800
#define NC 2
#define KPOOL 280
#define ATT_SCALE 0.1f

// ---------------------------------------------------------------- preprocess
__global__ __launch_bounds__(256) void pre_reduce_kernel(const float* __restrict__ in,
                                                         float* __restrict__ meanb,
                                                         float* __restrict__ stdb) {
  int b = blockIdx.x;
  const float* p = in + (size_t)b * ROI * (2 * ROI);
  double s = 0.0, ss = 0.0;
  const int n = ROI * ROI;
  for (int e = threadIdx.x; e < n; e += blockDim.x) {
    int r = e / ROI, c = e % ROI;
    float v = log10f(p[(size_t)r * (2 * ROI) + ROI + c] + 1.0f);
    s += v; ss += (double)v * (double)v;
  }
  __shared__ double rs[256], rss[256];
  rs[threadIdx.x] = s; rss[threadIdx.x] = ss;
  __syncthreads();
  for (int st = 128; st > 0; st >>= 1) {
    if (threadIdx.x < st) { rs[threadIdx.x] += rs[threadIdx.x + st]; rss[threadIdx.x] += rss[threadIdx.x + st]; }
    __syncthreads();
  }
  if (threadIdx.x == 0) {
    double mean = rs[0] / n;
    double var = (rss[0] - rs[0] * rs[0] / n) / (double)(n - 1);
    meanb[b] = (float)mean;
    stdb[b]  = (float)(sqrt(var) + 1e-6);
  }
}

__global__ __launch_bounds__(256) void build_xm_kernel(const float* __restrict__ in,
                                                       const float* __restrict__ sel,
                                                       const float* __restrict__ meanb,
                                                       const float* __restrict__ stdb,
                                                       float* __restrict__ X, float* __restrict__ M) {
  size_t e = (size_t)blockIdx.x * blockDim.x + threadIdx.x;
  const size_t total = (size_t)NB * ROI * ROI;
  if (e >= total) return;
  int c = (int)(e % ROI);
  int r = (int)((e / ROI) % ROI);
  int b = (int)(e / ((size_t)ROI * ROI));
  const float* row = in + ((size_t)b * ROI + r) * (2 * ROI);
  X[e] = row[c];
  float v = log10f(row[ROI + c] + 1.0f);
  float sg = 1.0f / (1.0f + expf(-sel[r * ROI + c]));
  M[e] = ((v - meanb[b]) / stdb[b]) * sg;
}

// ---------------------------------------------------------------- QKV weight pack
__global__ __launch_bounds__(256) void pack_qkv_kernel(const float* __restrict__ wq, const float* __restrict__ wk,
                                                       const float* __restrict__ wv, float* __restrict__ wp) {
  int e = blockIdx.x * 256 + threadIdx.x;
  if (e >= ROI * 3 * ROI) return;
  int k = e / (3 * ROI), c = e % (3 * ROI);
  float v;
  if (c < ROI) v = wq[k * ROI + c];
  else if (c < 2 * ROI) v = wk[k * ROI + c - ROI];
  else v = wv[k * ROI + c - 2 * ROI];
  wp[e] = v;
}

// ---------------------------------------------------------------- GEMM  256x64 tile, 16x4 micro
// C[M,N] = A[M,K] @ W[K,N]  (+bias, +res, +gelu per EPI). M%256==0, K%16==0, N guarded.
#define GBM 256
#define GBN 64
#define GBK 16
#define APAD 260

template<int EPI>
__global__ __launch_bounds__(256) void gemm_kernel(const float* __restrict__ A, const float* __restrict__ W,
                                                   const float* __restrict__ bias, const float* __restrict__ res,
                                                   float* __restrict__ C, int M, int N, int K) {
  __shared__ __align__(16) float As[GBK][APAD];   // transposed A tile [k][row], padded
  __shared__ __align__(16) float Bs[GBK][GBN];
  const int tid = threadIdx.x;
  const int bm = blockIdx.y * GBM;
  const int bn = blockIdx.x * GBN;
  const int trg = tid >> 4;        // row group: rows trg*16 .. +15
  const int tc  = tid & 15;        // col group: cols tc*4 .. +3
  float acc[16][4] = {};

  const int sar = tid >> 2;        // A-stage: base row (iter adds 64)
  const int sac = (tid & 3) << 2;  // A-stage: k offset (4 floats)
  const int sbk = tid >> 4;        // B-stage: k row
  const int sbc = (tid & 15) << 2; // B-stage: col offset

  for (int k0 = 0; k0 < K; k0 += GBK) {
#pragma unroll
    for (int it = 0; it < 4; ++it) {
      int r = it * 64 + sar;
      float4 av = *(const float4*)(A + (size_t)(bm + r) * K + k0 + sac);
      As[sac + 0][r] = av.x; As[sac + 1][r] = av.y;
      As[sac + 2][r] = av.z; As[sac + 3][r] = av.w;
    }
    {
      const float* wrow = W + (size_t)(k0 + sbk) * N;
      int wc = bn + sbc;
      float4 wv;
      if (wc + 3 < N) {
        wv = *(const float4*)(wrow + wc);
      } else {
        wv.x = (wc + 0 < N) ? wrow[wc + 0] : 0.f;
        wv.y = (wc + 1 < N) ? wrow[wc + 1] : 0.f;
        wv.z = (wc + 2 < N) ? wrow[wc + 2] : 0.f;
        wv.w = (wc + 3 < N) ? wrow[wc + 3] : 0.f;
      }
      *(float4*)&Bs[sbk][sbc] = wv;
    }
    __syncthreads();
#pragma unroll
    for (int kk = 0; kk < GBK; ++kk) {
      float4 b4 = *(const float4*)&Bs[kk][tc << 2];
      float4 a0 = *(const float4*)&As[kk][trg * 16 + 0];
      float4 a1 = *(const float4*)&As[kk][trg * 16 + 4];
      float4 a2 = *(const float4*)&As[kk][trg * 16 + 8];
      float4 a3 = *(const float4*)&As[kk][trg * 16 + 12];
      const float af[16] = {a0.x, a0.y, a0.z, a0.w, a1.x, a1.y, a1.z, a1.w,
                            a2.x, a2.y, a2.z, a2.w, a3.x, a3.y, a3.z, a3.w};
#pragma unroll
      for (int i = 0; i < 16; ++i) {
        acc[i][0] += af[i] * b4.x; acc[i][1] += af[i] * b4.y;
        acc[i][2] += af[i] * b4.z; acc[i][3] += af[i] * b4.w;
      }
    }
    __syncthreads();
  }

  // epilogue
  const int col = bn + (tc << 2);
  float bv[4] = {0.f, 0.f, 0.f, 0.f};
  if (EPI >= 1) {
#pragma unroll
    for (int j = 0; j < 4; ++j) bv[j] = (col + j < N) ? bias[col + j] : 0.f;
  }
#pragma unroll
  for (int i = 0; i < 16; ++i) {
    int row = bm + trg * 16 + i;
    if (col + 3 < N) {
      float4 v = make_float4(acc[i][0] + bv[0], acc[i][1] + bv[1], acc[i][2] + bv[2], acc[i][3] + bv[3]);
      if (EPI == 2) {
        float4 r4 = *(const float4*)(res + (size_t)row * N + col);
        v.x += r4.x; v.y += r4.y; v.z += r4.z; v.w += r4.w;
      }
      if (EPI == 3) {
        v.x = 0.5f * v.x * (1.0f + erff(v.x * 0.70710678118654752f));
        v.y = 0.5f * v.y * (1.0f + erff(v.y * 0.70710678118654752f));
        v.z = 0.5f * v.z * (1.0f + erff(v.z * 0.70710678118654752f));
        v.w = 0.5f * v.w * (1.0f + erff(v.w * 0.70710678118654752f));
      }
      *(float4*)(C + (size_t)row * N + col) = v;
    } else {
#pragma unroll
      for (int j = 0; j < 4; ++j) {
        if (col + j < N) {
          float v = acc[i][j] + bv[j];
          if (EPI == 2) v += res[(size_t)row * N + col + j];
          if (EPI == 3) v = 0.5f * v * (1.0f + erff(v * 0.70710678118654752f));
          C[(size_t)row * N + col + j] = v;
        }
      }
    }
  }
}

// ---------------------------------------------------------------- fused flash attention
// block = 256 threads, 64 query rows of one (b, h). Tiles over 64 keys. ldq = QKV row stride.
#define BI 64
#define BJ 64

__global__ __launch_bounds__(256) void fattn_kernel(const float* __restrict__ Q, const float* __restrict__ K,
                                                    const float* __restrict__ V, const float* __restrict__ Mm,
                                                    float* __restrict__ O, int N, int ldq) {
  __shared__ __align__(16) float Qst[DH][BI];
  __shared__ __align__(16) float KV[BJ * 128];
  __shared__ __align__(16) float Ss[BI][68];
  float (*Kst)[BJ] = (float (*)[BJ])KV;
  float (*Vs)[128] = (float (*)[128])KV;

  const int tid = threadIdx.x;
  const int tr = tid >> 4;
  const int tc = tid & 15;
  const int i0 = blockIdx.x * BI;
  const int h  = blockIdx.y;
  const int b  = blockIdx.z;
  const int HD = HEADS * DH;

  const float* Qb = Q + (size_t)b * N * ldq + h * DH;
  const float* Kb = K + (size_t)b * N * ldq + h * DH;
  const float* Vb = V + (size_t)b * N * ldq + h * DH;

  for (int e = tid; e < (DH / 4) * BI; e += 256) {
    int c = e >> 6, r = e & 63;
    int gi = i0 + r; if (gi >= N) gi = N - 1;
    float4 v = *(const float4*)(Qb + (size_t)gi * ldq + 4 * c);
    Qst[4 * c + 0][r] = v.x; Qst[4 * c + 1][r] = v.y;
    Qst[4 * c + 2][r] = v.z; Qst[4 * c + 3][r] = v.w;
  }

  float m_i[4], l_i[4];
  float oa[4][4] = {};
  float ob[4][4] = {};
#pragma unroll
  for (int i = 0; i < 4; ++i) { m_i[i] = -INFINITY; l_i[i] = 0.f; }

  const int njt = (N + BJ - 1) / BJ;
  for (int jt = 0; jt < njt; ++jt) {
    const int j0 = jt * BJ;
    __syncthreads();
    for (int e = tid; e < (DH / 4) * BJ; e += 256) {
      int c = e >> 6, r = e & 63;
      int gj = j0 + r; if (gj >= N) gj = N - 1;
      float4 v = *(const float4*)(Kb + (size_t)gj * ldq + 4 * c);
      Kst[4 * c + 0][r] = v.x; Kst[4 * c + 1][r] = v.y;
      Kst[4 * c + 2][r] = v.z; Kst[4 * c + 3][r] = v.w;
    }
    __syncthreads();

    float sacc[4][4] = {};
#pragma unroll 4
    for (int kk = 0; kk < DH; ++kk) {
      float4 a  = *(const float4*)&Qst[kk][4 * tr];
      float4 bb = *(const float4*)&Kst[kk][4 * tc];
      sacc[0][0] += a.x * bb.x; sacc[0][1] += a.x * bb.y; sacc[0][2] += a.x * bb.z; sacc[0][3] += a.x * bb.w;
      sacc[1][0] += a.y * bb.x; sacc[1][1] += a.y * bb.y; sacc[1][2] += a.y * bb.z; sacc[1][3] += a.y * bb.w;
      sacc[2][0] += a.z * bb.x; sacc[2][1] += a.z * bb.y; sacc[2][2] += a.z * bb.z; sacc[2][3] += a.z * bb.w;
      sacc[3][0] += a.w * bb.x; sacc[3][1] += a.w * bb.y; sacc[3][2] += a.w * bb.z; sacc[3][3] += a.w * bb.w;
    }

    const float* Mbase = Mm + (size_t)b * N * N;
#pragma unroll
    for (int i = 0; i < 4; ++i) {
      int gi = i0 + 4 * tr + i; if (gi >= N) gi = N - 1;
      const float* Mr = Mbase + (size_t)gi * N + j0 + 4 * tc;
      float mv[4];
      if (j0 + 4 * tc + 3 < N) {
        float4 m4 = *(const float4*)Mr;
        mv[0] = m4.x; mv[1] = m4.y; mv[2] = m4.z; mv[3] = m4.w;
      } else {
#pragma unroll
        for (int q = 0; q < 4; ++q) mv[q] = (j0 + 4 * tc + q < N) ? Mr[q] : 0.f;
      }
      float p[4];
      float rm = -INFINITY;
#pragma unroll
      for (int q = 0; q < 4; ++q) {
        float s = (j0 + 4 * tc + q < N) ? sacc[i][q] * ATT_SCALE * (1.0f + mv[q]) : -INFINITY;
        p[q] = s;
        rm = fmaxf(rm, s);
      }
      rm = fmaxf(rm, __shfl_xor(rm, 1, 16));
      rm = fmaxf(rm, __shfl_xor(rm, 2, 16));
      rm = fmaxf(rm, __shfl_xor(rm, 4, 16));
      rm = fmaxf(rm, __shfl_xor(rm, 8, 16));
      float nm = fmaxf(m_i[i], rm);
      float f = expf(m_i[i] - nm);
      float ts = 0.f;
#pragma unroll
      for (int q = 0; q < 4; ++q) { float e = expf(p[q] - nm); p[q] = e; ts += e; }
      ts += __shfl_xor(ts, 1, 16);
      ts += __shfl_xor(ts, 2, 16);
      ts += __shfl_xor(ts, 4, 16);
      ts += __shfl_xor(ts, 8, 16);
      l_i[i] = l_i[i] * f + ts;
      m_i[i] = nm;
#pragma unroll
      for (int q = 0; q < 4; ++q) { oa[i][q] *= f; ob[i][q] *= f; }
      *(float4*)&Ss[4 * tr + i][4 * tc] = make_float4(p[0], p[1], p[2], p[3]);
    }
    __syncthreads();

    for (int e = tid; e < (DH / 4) * BJ; e += 256) {
      int c = e % 25, r = e / 25;
      int gj = j0 + r; if (gj >= N) gj = N - 1;
      *(float4*)&Vs[r][4 * c] = *(const float4*)(Vb + (size_t)gj * ldq + 4 * c);
    }
    __syncthreads();

#pragma unroll 2
    for (int jj = 0; jj < BJ / 4; ++jj) {
      float4 p0 = *(const float4*)&Ss[4 * tr + 0][4 * jj];
      float4 p1 = *(const float4*)&Ss[4 * tr + 1][4 * jj];
      float4 p2 = *(const float4*)&Ss[4 * tr + 2][4 * jj];
      float4 p3 = *(const float4*)&Ss[4 * tr + 3][4 * jj];
      float pv[4][4] = {{p0.x, p0.y, p0.z, p0.w}, {p1.x, p1.y, p1.z, p1.w},
                        {p2.x, p2.y, p2.z, p2.w}, {p3.x, p3.y, p3.z, p3.w}};
#pragma unroll
      for (int q = 0; q < 4; ++q) {
        int j = 4 * jj + q;
        float4 va = *(const float4*)&Vs[j][4 * tc];
        float4 vb = *(const float4*)&Vs[j][64 + 4 * tc];
#pragma unroll
        for (int i = 0; i < 4; ++i) {
          oa[i][0] += pv[i][q] * va.x; oa[i][1] += pv[i][q] * va.y;
          oa[i][2] += pv[i][q] * va.z; oa[i][3] += pv[i][q] * va.w;
          ob[i][0] += pv[i][q] * vb.x; ob[i][1] += pv[i][q] * vb.y;
          ob[i][2] += pv[i][q] * vb.z; ob[i][3] += pv[i][q] * vb.w;
        }
      }
    }
  }

  float* Ob = O + (size_t)b * N * (HEADS * DH) + h * DH;
#pragma unroll
  for (int i = 0; i < 4; ++i) {
    int gi = i0 + 4 * tr + i;
    if (gi < N) {
      float inv = 1.0f / l_i[i];
      float4 w = make_float4(oa[i][0] * inv, oa[i][1] * inv, oa[i][2] * inv, oa[i][3] * inv);
      *(float4*)(Ob + (size_t)gi * (HEADS * DH) + 4 * tc) = w;
      if (tc < 9) {
        float4 w2 = make_float4(ob[i][0] * inv, ob[i][1] * inv, ob[i][2] * inv, ob[i][3] * inv);
        *(float4*)(Ob + (size_t)gi * (HEADS * DH) + 64 + 4 * tc) = w2;
      }
    }
  }
}

// ---------------------------------------------------------------- layernorm
__global__ __launch_bounds__(128) void ln_kernel(const float* __restrict__ Y, const float* __restrict__ g,
                                                 const float* __restrict__ bta, float* __restrict__ X) {
  int row = blockIdx.x;
  const float* y = Y + (size_t)row * ROI;
  float* x = X + (size_t)row * ROI;
  int tid = threadIdx.x;
  __shared__ float red[128];
  float s = 0.f;
  for (int c = tid; c < ROI; c += 128) s += y[c];
  red[tid] = s; __syncthreads();
  for (int st = 64; st > 0; st >>= 1) { if (tid < st) red[tid] += red[tid + st]; __syncthreads(); }
  float mu = red[0] / ROI;
  __syncthreads();
  float v = 0.f;
  for (int c = tid; c < ROI; c += 128) { float d = y[c] - mu; v += d * d; }
  red[tid] = v; __syncthreads();
  for (int st = 64; st > 0; st >>= 1) { if (tid < st) red[tid] += red[tid + st]; __syncthreads(); }
  float rstd = rsqrtf(red[0] / ROI + 1e-5f);
  for (int c = tid; c < ROI; c += 128) x[c] = (y[c] - mu) * rstd * g[c] + bta[c];
}

// ---------------------------------------------------------------- classifier head
__global__ __launch_bounds__(128) void cls_kernel(const float* __restrict__ X, const float* __restrict__ r1w,
                                                  const float* __restrict__ r1b, const float* __restrict__ r2w,
                                                  const float* __restrict__ r2b, float* __restrict__ probs, int N) {
  int b = blockIdx.x, tid = threadIdx.x;
  __shared__ float gf[ROI];
  __shared__ float hid[128];
  for (int c = tid; c < ROI; c += 128) {
    float s = 0.f;
    for (int n = 0; n < N; ++n) s += X[((size_t)b * N + n) * ROI + c];
    gf[c] = s / (float)N;
  }
  __syncthreads();
  {
    float a = r1b[tid];
    for (int k = 0; k < ROI; ++k) a += gf[k] * r1w[k * 128 + tid];
    hid[tid] = (a >= 0.f) ? a : 0.01f * a;
  }
  __syncthreads();
  if (tid < NC) {
    float l = r2b[tid];
    for (int k = 0; k < 128; ++k) l += hid[k] * r2w[k * NC + tid];
    gf[tid] = l;
  }
  __syncthreads();
  if (tid == 0) {
    float m = fmaxf(gf[0], gf[1]);
    float e0 = expf(gf[0] - m), e1 = expf(gf[1] - m);
    float inv = 1.f / (e0 + e1);
    probs[b * NC + 0] = e0 * inv;
    probs[b * NC + 1] = e1 * inv;
  }
}

// ---------------------------------------------------------------- pooling
__global__ __launch_bounds__(128) void score_kernel(const float* __restrict__ M, const float* __restrict__ X,
                                                    const float* __restrict__ pws, const float* __restrict__ pwf,
                                                    const float* __restrict__ pmw, const float* __restrict__ pmb,
                                                    float* __restrict__ scores) {
  int i = blockIdx.x, b = blockIdx.y, tid = threadIdx.x;
  const float* mr = M + ((size_t)b * ROI + i) * ROI;
  const float* xr = X + ((size_t)b * ROI + i) * ROI;
  float s1 = 0.f, s2 = 0.f;
  for (int j = tid; j < ROI; j += 128) { s1 += mr[j] * pws[j]; s2 += xr[j] * pwf[j]; }
  __shared__ float r1[128], r2[128];
  r1[tid] = s1; r2[tid] = s2; __syncthreads();
  for (int st = 64; st > 0; st >>= 1) {
    if (tid < st) { r1[tid] += r1[tid + st]; r2[tid] += r2[tid + st]; }
    __syncthreads();
  }
  if (tid == 0) {
    float a = fabsf(r1[0]), c = fabsf(r2[0]);
    float z = a * pmw[0] + c * pmw[1] + pmb[0];
    scores[b * ROI + i] = 1.f / (1.f + expf(-z));
  }
}

__global__ __launch_bounds__(128) void select_kernel(const float* __restrict__ scores, int* __restrict__ idx) {
  int b = blockIdx.x, tid = threadIdx.x;
  __shared__ float sc[ROI];
  __shared__ int sel[ROI];
  for (int i = tid; i < ROI; i += 128) sc[i] = scores[b * ROI + i];
  __syncthreads();
  for (int i = tid; i < ROI; i += 128) {
    float si = sc[i];
    int rank = 0;
    for (int j = 0; j < ROI; ++j) {
      float sj = sc[j];
      rank += (sj > si) || (sj == si && j < i);
    }
    sel[i] = (rank < KPOOL) ? 1 : 0;
  }
  __syncthreads();
  for (int i = tid; i < ROI; i += 128) {
    if (sel[i]) {
      int pos = 0;
      for (int j = 0; j < i; ++j) pos += sel[j];
      idx[b * KPOOL + pos] = i;
    }
  }
}

__global__ __launch_bounds__(128) void gatherx_kernel(const float* __restrict__ X, const float* __restrict__ scores,
                                                      const int* __restrict__ idx, float* __restrict__ Xp) {
  int p = blockIdx.x % KPOOL, b = blockIdx.x / KPOOL, tid = threadIdx.x;
  int src = idx[b * KPOOL + p];
  float sw = scores[b * ROI + src];
  const float* xr = X + ((size_t)b * ROI + src) * ROI;
  float* o = Xp + ((size_t)b * KPOOL + p) * ROI;
  for (int c = tid; c < ROI; c += 128) o[c] = xr[c] * sw;
}

__global__ __launch_bounds__(128) void gatherm_kernel(const float* __restrict__ M, const int* __restrict__ idx,
                                                      float* __restrict__ Mp) {
  int p = blockIdx.x % KPOOL, b = blockIdx.x / KPOOL, tid = threadIdx.x;
  __shared__ int id[KPOOL];
  for (int q = tid; q < KPOOL; q += 128) id[q] = idx[b * KPOOL + q];
  __syncthreads();
  int src = idx[b * KPOOL + p];
  const float* mr = M + ((size_t)b * ROI + src) * ROI;
  float* o = Mp + ((size_t)b * KPOOL + p) * KPOOL;
  for (int q = tid; q < KPOOL; q += 128) o[q] = mr[id[q]];
}

// ---------------------------------------------------------------- final output
__global__ __launch_bounds__(128) void final_kernel(const float* __restrict__ X, const float* __restrict__ probs,
                                                    float* __restrict__ out, int N) {
  int b = blockIdx.x, tid = threadIdx.x;
  __shared__ float f[ROI];
  __shared__ float red[128];
  for (int c = tid; c < ROI; c += 128) {
    float s = 0.f;
    for (int n = 0; n < N; ++n) s += X[((size_t)b * N + n) * ROI + c];
    f[c] = s / (float)N;
  }
  __syncthreads();
  float ls = 0.f;
  for (int c = tid; c < ROI; c += 128) ls += f[c] * f[c];
  red[tid] = ls; __syncthreads();
  for (int st = 64; st > 0; st >>= 1) { if (tid < st) red[tid] += red[tid + st]; __syncthreads(); }
  float inv = 1.f / fmaxf(sqrtf(red[0]), 1e-12f);
  for (int c = tid; c < ROI; c += 128) out[b * ROI + c] = f[c] * inv;
  if (tid < NC) out[NB * ROI + b * NC + tid] = 0.5f * (probs[b * NC + tid] + probs[NB * NC + b * NC + tid]);
}

// ---------------------------------------------------------------- host orchestration
static inline void gemm_launch0(const float* A, const float* W, float* C, int M, int N, int K, hipStream_t st) {
  dim3 g((N + GBN - 1) / GBN, M / GBM);
  gemm_kernel<0><<<g, 256, 0, st>>>(A, W, nullptr, nullptr, C, M, N, K);
}
static inline void gemm_launch2(const float* A, const float* W, const float* bias, const float* res, float* C,
                                int M, int N, int K, hipStream_t st) {
  dim3 g((N + GBN - 1) / GBN, M / GBM);
  gemm_kernel<2><<<g, 256, 0, st>>>(A, W, bias, res, C, M, N, K);
}
static inline void gemm_launch3(const float* A, const float* W, const float* bias, float* C,
                                int M, int N, int K, hipStream_t st) {
  dim3 g((N + GBN - 1) / GBN, M / GBM);
  gemm_kernel<3><<<g, 256, 0, st>>>(A, W, bias, nullptr, C, M, N, K);
}

extern "C" void kernel_launch(void* const* d_in, const int* in_sizes, int n_in,
                              void* d_out, int out_size, void* d_ws, size_t ws_size,
                              hipStream_t stream) {
  const float* in  = (const float*)d_in[0];
  const float* sel = (const float*)d_in[1];
  const float* wq  = (const float*)d_in[2];
  const float* wk  = (const float*)d_in[3];
  const float* wv  = (const float*)d_in[4];
  const float* wo  = (const float*)d_in[5];
  const float* bo  = (const float*)d_in[6];
  const float* w1  = (const float*)d_in[7];
  const float* b1  = (const float*)d_in[8];
  const float* w2  = (const float*)d_in[9];
  const float* b2  = (const float*)d_in[10];
  const float* lng = (const float*)d_in[11];
  const float* lnb = (const float*)d_in[12];
  const float* pws = (const float*)d_in[13];
  const float* pwf = (const float*)d_in[14];
  const float* pmw = (const float*)d_in[15];
  const float* pmb = (const float*)d_in[16];
  const float* r1w = (const float*)d_in[17];
  const float* r1b = (const float*)d_in[18];
  const float* r2w = (const float*)d_in[19];
  const float* r2b = (const float*)d_in[20];
  float* out = (float*)d_out;

  float* ws = (float*)d_ws;
  const size_t AT = (size_t)NB * ROI * ROI;  // 10,240,000 floats per slab
  float* A0 = ws;
  float* A1 = ws + AT;
  float* A2 = ws + 2 * AT;
  float* A3 = ws + 3 * AT;
  float* A4 = ws + 4 * AT;
  float* A5 = ws + 5 * AT;
  float* smalls = ws + 6 * AT;
  float* meanb = smalls;                 // 64
  float* stdb  = smalls + 64;            // 64
  float* scores = smalls + 128;          // 64*400
  int*   idx = (int*)(smalls + 128 + NB * ROI);        // 64*280 ints
  float* probs = smalls + 128 + NB * ROI + NB * KPOOL; // 2*64*2

  const int NQKV = 3 * ROI;  // 1200
  const int packGrid = (ROI * NQKV + 255) / 256;

  pre_reduce_kernel<<<NB, 256, 0, stream>>>(in, meanb, stdb);
  build_xm_kernel<<<(int)((AT + 255) / 256), 256, 0, stream>>>(in, sel, meanb, stdb, A0, A1);

  // ---------------- depth 0: N=400, x=A0, m=A1
  {
    const int N = ROI;
    const int Mtok = NB * N;  // 25600
    const float* x = A0;
    const float* m = A1;
    float* wp = A5;            // packed QKV weights (dead once QKV gemm completes)
    pack_qkv_kernel<<<packGrid, 256, 0, stream>>>(wq, wk, wv, wp);
    float* QKV = A2;           // spans A2..A4: Mtok x 1200
    gemm_launch0(x, wp, QKV, Mtok, NQKV, ROI, stream);
    float* O = A5;             // over wp (dead)
    fattn_kernel<<<dim3((N + BI - 1) / BI, HEADS, NB), 256, 0, stream>>>(
        QKV, QKV + ROI, QKV + 2 * ROI, m, O, N, NQKV);
    float* Xa = A2;            // over QKV
    gemm_launch2(O, wo + 0, bo + 0, x, Xa, Mtok, ROI, ROI, stream);
    float* H = A3;             // spans A3..A4
    gemm_launch3(Xa, w1 + 0, b1 + 0, H, Mtok, HIDF, ROI, stream);
    float* Y = A5;             // over O
    gemm_launch2(H, w2 + 0, b2 + 0, Xa, Y, Mtok, ROI, HIDF, stream);
    float* Xn = A0;            // over x
    ln_kernel<<<Mtok, 128, 0, stream>>>(Y, lng + 0, lnb + 0, Xn);
    cls_kernel<<<NB, 128, 0, stream>>>(Xn, r1w + 0, r1b + 0, r2w + 0, r2b + 0, probs, N);
    score_kernel<<<dim3(ROI, NB), 128, 0, stream>>>(m, Xn, pws, pwf, pmw, pmb, scores);
    select_kernel<<<NB, 128, 0, stream>>>(scores, idx);
    gatherx_kernel<<<NB * KPOOL, 128, 0, stream>>>(Xn, scores, idx, A3);  // Xp -> A3
    gatherm_kernel<<<NB * KPOOL, 128, 0, stream>>>(m, idx, A4);            // Mp -> A4
  }

  // ---------------- depth 1: N=280, x=A3, m=A4
  {
    const int N = KPOOL;
    const int Mtok = NB * N;  // 17920
    const float* x = A3;
    const float* m = A4;
    const int d = 1;
    const float* wq1 = wq + (size_t)d * ROI * ROI;
    const float* wk1 = wk + (size_t)d * ROI * ROI;
    const float* wv1 = wv + (size_t)d * ROI * ROI;
    const float* wo1 = wo + (size_t)d * ROI * ROI;
    const float* bo1 = bo + (size_t)d * ROI;
    const float* w11 = w1 + (size_t)d * ROI * HIDF;
    const float* b11 = b1 + (size_t)d * HIDF;
    const float* w21 = w2 + (size_t)d * HIDF * ROI;
    const float* b21 = b2 + (size_t)d * ROI;
    const float* lng1 = lng + (size_t)d * ROI;
    const float* lnb1 = lnb + (size_t)d * ROI;
    const float* r1w1 = r1w + (size_t)d * ROI * 128;
    const float* r1b1 = r1b + (size_t)d * 128;
    const float* r2w1 = r2w + (size_t)d * 128 * NC;
    const float* r2b1 = r2b + (size_t)d * NC;

    float* wp = A5;            // packed QKV weights depth 1
    pack_qkv_kernel<<<packGrid, 256, 0, stream>>>(wq1, wk1, wv1, wp);
    float* QKV = A0;           // spans A0..A2: 17920 x 1200 (2.1 slabs)
    gemm_launch0(x, wp, QKV, Mtok, NQKV, ROI, stream);
    float* O = A5;             // over wp
    fattn_kernel<<<dim3((N + BI - 1) / BI, HEADS, NB), 256, 0, stream>>>(
        QKV, QKV + ROI, QKV + 2 * ROI, m, O, N, NQKV);
    float* Xa = A0;            // over QKV
    gemm_launch2(O, wo1, bo1, x, Xa, Mtok, ROI, ROI, stream);
    float* H = A1;             // spans A1..A2
    gemm_launch3(Xa, w11, b11, H, Mtok, HIDF, ROI, stream);
    float* Y = A5;             // over O
    gemm_launch2(H, w21, b21, Xa, Y, Mtok, ROI, HIDF, stream);
    float* Xf = A1;            // over H
    ln_kernel<<<Mtok, 128, 0, stream>>>(Y, lng1, lnb1, Xf);
    cls_kernel<<<NB, 128, 0, stream>>>(Xf, r1w1, r1b1, r2w1, r2b1, probs + NB * NC, N);
    final_kernel<<<NB, 128, 0, stream>>>(Xf, probs, out, N);
  }
  (void)in_sizes; (void)n_in; (void)out_size; (void)ws_size;
}